// Round 3
// baseline (1094.700 us; speedup 1.0000x reference)
//
#include <hip/hip_runtime.h>

#define US unsigned short

typedef short bf16x8 __attribute__((ext_vector_type(8)));
typedef float f32x4 __attribute__((ext_vector_type(4)));

__device__ __forceinline__ float b2f(US u) {
  union { unsigned u; float f; } x; x.u = ((unsigned)u) << 16; return x.f;
}
__device__ __forceinline__ US f2b(float f) {
  union { float f; unsigned u; } x; x.f = f;
  unsigned r = x.u + 0x7FFFu + ((x.u >> 16) & 1u);
  return (US)(r >> 16);
}
__device__ __forceinline__ float lk(float v) { return v >= 0.f ? v : 0.2f * v; }

// flag-dependent input read: fl=1 -> buffers are float32, fl=0 -> bf16
__device__ __forceinline__ float ldin(const void* p, int i, int fl) {
  return fl ? ((const float*)p)[i] : b2f(((const US*)p)[i]);
}

// ---- ws byte offsets ----
#define O_W1 0          /* bf16 [256][768]: fc1_w | fc_m_a_w | fc1_b @744 | 0 */
#define O_W2 393216     /* bf16 [256][256] alpha-folded */
#define O_W3 524288
#define O_W4 655360
#define O_W5 786432     /* alpha5 row-scaled */
#define O_W6 917504
#define O_B2 1048576    /* f32[256] betas */
#define O_B3 1049600
#define O_B4 1050624
#define O_B6 1051648
#define O_VD 1052672    /* f32[256][4]: {a5*wvd0, a5*wvd1, a5*wvd2, b5} */
#define O_A2 1056800    /* f32[256] alphas (temp) */
#define O_A3 1057824
#define O_A4 1058848
#define O_A6 1059872
#define O_A5 1060896
#define O_B5 1061920
#define O_FLAG 1062944  /* int: 1 = inputs are f32, 0 = bf16 */

// dtype detector: decode first 512 uint16 of x as bf16; f32 data misread as
// bf16 gives ~90% wild values (NaN / |v|>1e3 / 0<|v|<1e-3), real bf16 ~0.
__global__ void detect_dtype(const void* x, char* ws) {
  if (threadIdx.x == 0) {
    const US* p = (const US*)x;
    int wild = 0;
    for (int i = 0; i < 512; ++i) {
      float v = b2f(p[i]);
      float a = fabsf(v);
      if (!(a <= 1e3f) || (a != 0.f && a < 1e-3f)) ++wild;  // NaN fails a<=1e3
    }
    *(int*)(ws + O_FLAG) = (wild > 32) ? 1 : 0;
  }
}

struct S1Args {
  const void* z;
  const void* w[10];
  const void* b[10];
};

// vectors: [a2,a3,a4,a6, b2,b3,b4,b6, a5, b5], each out[k] = dot(z, W[k][:]) + B[k]
__global__ void setup_vec(S1Args a, char* ws) {
  const int outoff[10] = {O_A2, O_A3, O_A4, O_A6, O_B2, O_B3, O_B4, O_B6, O_A5, O_B5};
  int fl = *(const int*)(ws + O_FLAG);
  int v = blockIdx.x, k = threadIdx.x;
  const void* W = a.w[v];
  float acc = ldin(a.b[v], k, fl);
  for (int s = 0; s < 128; ++s) acc += ldin(a.z, s, fl) * ldin(W, k * 128 + s, fl);
  *(float*)(ws + outoff[v] + k * 4) = acc;
}

struct S2Args {
  const void *fc1_w, *fc1_b, *m_w, *w2, *w3, *w4, *w5, *w6, *vdw;
};

__global__ void setup_w(S2Args a, char* ws) {
  int fl = *(const int*)(ws + O_FLAG);
  int b = blockIdx.x, t = threadIdx.x;
  if (b < 256) {                       // W1p row n = b, 768 wide
    int n = b;
    US* W1p = (US*)(ws + O_W1);
    for (int i = 0; i < 3; ++i) {
      int k = t + i * 256;
      float v;
      if (k < 64) v = ldin(a.fc1_w, n * 64 + k, fl);
      else if (k < 744) v = ldin(a.m_w, n * 680 + k - 64, fl);
      else if (k == 744) v = ldin(a.fc1_b, n, fl);
      else v = 0.f;
      W1p[n * 768 + k] = f2b(v);
    }
  } else if (b < 1536) {               // layers 2,3,4,5,6 alpha-folded
    int li = (b - 256) >> 8;           // 0..4 -> W2,W3,W4,W5,W6
    int n = (b - 256) & 255;
    int k = t;
    const void* Wsrc = (li == 0) ? a.w2 : (li == 1) ? a.w3 : (li == 2) ? a.w4
                      : (li == 3) ? a.w5 : a.w6;
    const int aoff[5] = {O_A2, O_A3, O_A4, O_A5, O_A6};
    US* Wdst = (US*)(ws + O_W2 + li * 131072);
    float alpha = (li == 3) ? *(const float*)(ws + O_A5 + n * 4)     // row scale
                            : *(const float*)(ws + aoff[li] + k * 4); // col scale
    Wdst[n * 256 + k] = f2b(ldin(Wsrc, n * 256 + k, fl) * alpha);
  } else {                             // vdpack
    int n = t;
    float a5 = *(const float*)(ws + O_A5 + n * 4);
    float b5 = *(const float*)(ws + O_B5 + n * 4);
    float* vp = (float*)(ws + O_VD + n * 16);
    vp[0] = a5 * ldin(a.vdw, n * 3 + 0, fl);
    vp[1] = a5 * ldin(a.vdw, n * 3 + 1, fl);
    vp[2] = a5 * ldin(a.vdw, n * 3 + 2, fl);
    vp[3] = b5;
  }
}

// Main fused kernel: 512 blocks x 512 threads, 256 rows/block.
// LDS: fAct[256][256] bf16 (xor-swizzled 16B chunks) = 128KB, + 2x16KB weight slice dbuf.
__global__ __launch_bounds__(512, 2) void mlp_main(
    const void* __restrict__ x, const void* __restrict__ rdir, const void* __restrict__ m,
    const void* __restrict__ wsig, const void* __restrict__ bsig,
    const void* __restrict__ wout, const void* __restrict__ bout,
    const char* __restrict__ ws, void* __restrict__ out) {
  __shared__ US lds[81920];  // 160 KB exactly
  const int fl = *(const int*)(ws + O_FLAG);
  const int tid = threadIdx.x;
  const int wave = tid >> 6, lane = tid & 63;
  const int l16 = lane & 15, q = lane >> 4;
  const int wr = wave & 3;    // row group: 64 rows each
  const int wcg = wave >> 2;  // col group: 128 cols each
  const int R0 = blockIdx.x * 256;

  const US* W1p = (const US*)(ws + O_W1);
  const US* W2p = (const US*)(ws + O_W2);
  const US* W3p = (const US*)(ws + O_W3);
  const US* W4p = (const US*)(ws + O_W4);
  const US* W5p = (const US*)(ws + O_W5);
  const US* W6p = (const US*)(ws + O_W6);

  f32x4 acc[4][8];

  const int srow = lane >> 2, skk = (lane & 3) * 8;

  auto loadW = [&](const US* W, int KS, int s, bf16x8 v[2]) {
#pragma unroll
    for (int it = 0; it < 2; ++it) {
      int n = (wave * 2 + it) * 16 + srow;
      v[it] = *(const bf16x8*)(W + n * KS + s * 32 + skk);
    }
  };
  auto storeW = [&](int buf, const bf16x8 v[2]) {
#pragma unroll
    for (int it = 0; it < 2; ++it)
      *(bf16x8*)&lds[65536 + buf * 8192 + (wave * 2 + it) * 512 + lane * 8] = v[it];
  };
  auto loadXM = [&](int s, bf16x8 v[2]) {   // layer-1 A rows: x | m | bias-one | 0
#pragma unroll
    for (int it = 0; it < 2; ++it) {
      int g = R0 + (wave * 2 + it) * 16 + srow;
      const void* base = nullptr;
      int off = 0;
      if (s < 2) { base = x; off = g * 64 + s * 32 + skk; }
      else if (s < 23) { base = m; off = g * 680 + (s * 32 - 64) + skk; }
      else if (skk == 0) { base = m; off = g * 680 + 672; }
      if (base) {
        if (fl) {
          const float* p = (const float*)base + off;
          bf16x8 t;
#pragma unroll
          for (int j = 0; j < 8; ++j) t[j] = (short)f2b(p[j]);
          v[it] = t;
        } else {
          v[it] = *(const bf16x8*)((const US*)base + off);
        }
      } else {
        bf16x8 t = {0, 0, 0, 0, 0, 0, 0, 0};
        if (skk == 8) t[0] = (short)0x3F80;   // k==744 -> 1.0 (bias multiplier)
        v[it] = t;
      }
    }
  };
  auto storeXM = [&](int buf, const bf16x8 v[2]) {
#pragma unroll
    for (int it = 0; it < 2; ++it)
      *(bf16x8*)&lds[buf * 8192 + (wave * 2 + it) * 512 + lane * 8] = v[it];
  };

  auto computeStep = [&](int s, int buf, bool fromXM) {
    bf16x8 a[4];
    if (fromXM) {
#pragma unroll
      for (int rt = 0; rt < 4; ++rt) {
        int r = wr * 64 + rt * 16 + l16;
        a[rt] = *(const bf16x8*)&lds[buf * 8192 + r * 32 + q * 8];
      }
    } else {
#pragma unroll
      for (int rt = 0; rt < 4; ++rt) {
        int r = wr * 64 + rt * 16 + l16;
        a[rt] = *(const bf16x8*)&lds[r * 256 + ((((s << 2) + q) ^ (r & 7)) << 3)];
      }
    }
    int wbase = 65536 + buf * 8192 + (wcg * 128 + l16) * 32 + q * 8;
#pragma unroll
    for (int nt = 0; nt < 8; ++nt) {
      bf16x8 b = *(const bf16x8*)&lds[wbase + nt * 512];
#pragma unroll
      for (int rt = 0; rt < 4; ++rt)
        acc[rt][nt] = __builtin_amdgcn_mfma_f32_16x16x32_bf16(a[rt], b, acc[rt][nt], 0, 0, 0);
    }
  };
  auto initZero = [&]() {
    f32x4 z = {0.f, 0.f, 0.f, 0.f};
#pragma unroll
    for (int rt = 0; rt < 4; ++rt)
#pragma unroll
      for (int nt = 0; nt < 8; ++nt) acc[rt][nt] = z;
  };
  auto initBeta = [&](int off) {
#pragma unroll
    for (int nt = 0; nt < 8; ++nt) {
      float bv = *(const float*)(ws + off + (wcg * 128 + nt * 16 + l16) * 4);
      f32x4 t = {bv, bv, bv, bv};
#pragma unroll
      for (int rt = 0; rt < 4; ++rt) acc[rt][nt] = t;
    }
  };
  auto runLayer = [&](const US* W) {
    bf16x8 v[2];
    loadW(W, 256, 0, v);
    storeW(0, v);
#pragma unroll 1
    for (int s = 0; s < 8; ++s) {
      bf16x8 nv[2];
      if (s < 7) loadW(W, 256, s + 1, nv);
      __syncthreads();
      computeStep(s, s & 1, false);
      if (s < 7) storeW((s + 1) & 1, nv);
    }
    __syncthreads();
  };
  auto epiAct = [&]() {  // leaky-relu -> fAct (bf16, swizzled), then barrier
#pragma unroll
    for (int nt = 0; nt < 8; ++nt) {
      int k = wcg * 128 + nt * 16 + l16;
#pragma unroll
      for (int rt = 0; rt < 4; ++rt) {
#pragma unroll
        for (int rg = 0; rg < 4; ++rg) {
          int r = wr * 64 + rt * 16 + q * 4 + rg;
          lds[r * 256 + ((((k >> 3) ^ (r & 7))) << 3) + (k & 7)] = f2b(lk(acc[rt][nt][rg]));
        }
      }
    }
    __syncthreads();
  };

  // ---- Layer 1: f1 = act(x@W1^T + m@Wm^T + b1), K = 768 staged ----
  initZero();
  {
    bf16x8 vw[2], va[2];
    loadW(W1p, 768, 0, vw);
    loadXM(0, va);
    storeW(0, vw);
    storeXM(0, va);
#pragma unroll 1
    for (int s = 0; s < 24; ++s) {
      bf16x8 nw[2], na[2];
      if (s < 23) { loadW(W1p, 768, s + 1, nw); loadXM(s + 1, na); }
      __syncthreads();
      computeStep(s, s & 1, true);
      if (s < 23) { storeW((s + 1) & 1, nw); storeXM((s + 1) & 1, na); }
    }
    __syncthreads();
  }
  epiAct();

  // ---- Layers 2..4 (modulated; alpha folded into W, beta via acc-init) ----
  initBeta(O_B2); runLayer(W2p); epiAct();
  initBeta(O_B3); runLayer(W3p); epiAct();
  initBeta(O_B4); runLayer(W4p); epiAct();

  // ---- sigma head from f4 (fAct) ----
  {
    int r = tid >> 1, hf = tid & 1, g = R0 + r;
    float sg = 0.f;
#pragma unroll
    for (int cc = 0; cc < 16; ++cc) {
      int ch = hf * 16 + cc;
      bf16x8 av = *(const bf16x8*)&lds[r * 256 + ((ch ^ (r & 7)) << 3)];
#pragma unroll
      for (int j = 0; j < 8; ++j) sg += b2f((US)av[j]) * ldin(wsig, ch * 8 + j, fl);
    }
    sg += __shfl_xor(sg, 1);
    if (!hf) {
      float v = sg + ldin(bsig, 0, fl);
      if (fl) ((float*)out)[g] = v; else ((US*)out)[g] = f2b(v);
    }
  }

  // ---- Layer 5: f5 = act(a5*(f4@W5^T + vd@Wvd^T) + b5); a5 folded into W5p/vdpack ----
  initZero();
  runLayer(W5p);
  if (tid < 96) ((float*)&lds[65536])[tid] = ldin(rdir, (R0 >> 3) * 3 + tid, fl);
  __syncthreads();
  {
    const float* rays = (const float*)&lds[65536];
    float ry[4][3];
#pragma unroll
    for (int rt = 0; rt < 4; ++rt) {
      int p = wr * 8 + rt * 2 + (q >> 1);  // pixel is constant across reg 0..3
      ry[rt][0] = rays[p * 3 + 0]; ry[rt][1] = rays[p * 3 + 1]; ry[rt][2] = rays[p * 3 + 2];
    }
#pragma unroll
    for (int nt = 0; nt < 8; ++nt) {
      int n = wcg * 128 + nt * 16 + l16;
      float4 vp = *(const float4*)(ws + O_VD + n * 16);
#pragma unroll
      for (int rt = 0; rt < 4; ++rt) {
#pragma unroll
        for (int rg = 0; rg < 4; ++rg) {
          float v = acc[rt][nt][rg] + ry[rt][0] * vp.x + ry[rt][1] * vp.y + ry[rt][2] * vp.z + vp.w;
          v = lk(v);
          int r = wr * 64 + rt * 16 + q * 4 + rg;
          lds[r * 256 + ((((n >> 3) ^ (r & 7))) << 3) + (n & 7)] = f2b(v);
        }
      }
    }
  }
  __syncthreads();  // fAct(f5) visible AND rays reads done before L6 staging reuses WS

  // ---- Layer 6 ----
  initBeta(O_B6); runLayer(W6p); epiAct();

  // ---- rgb head from f6 ----
  {
    int r = tid >> 1, hf = tid & 1, g = R0 + r;
    float c0 = 0.f, c1 = 0.f, c2 = 0.f;
#pragma unroll
    for (int cc = 0; cc < 16; ++cc) {
      int ch = hf * 16 + cc;
      bf16x8 av = *(const bf16x8*)&lds[r * 256 + ((ch ^ (r & 7)) << 3)];
#pragma unroll
      for (int j = 0; j < 8; ++j) {
        float f = b2f((US)av[j]);
        int ci = ch * 8 + j;
        c0 += f * ldin(wout, ci, fl);
        c1 += f * ldin(wout, 256 + ci, fl);
        c2 += f * ldin(wout, 512 + ci, fl);
      }
    }
    c0 += __shfl_xor(c0, 1); c1 += __shfl_xor(c1, 1); c2 += __shfl_xor(c2, 1);
    if (!hf) {
      float v0 = c0 + ldin(bout, 0, fl);
      float v1 = c1 + ldin(bout, 1, fl);
      float v2 = c2 + ldin(bout, 2, fl);
      if (fl) {
        float* o = (float*)out + 131072 + g * 3;
        o[0] = v0; o[1] = v1; o[2] = v2;
      } else {
        US* o = (US*)out + 131072 + g * 3;
        o[0] = f2b(v0); o[1] = f2b(v1); o[2] = f2b(v2);
      }
    }
  }
}

extern "C" void kernel_launch(void* const* d_in, const int* in_sizes, int n_in,
                              void* d_out, int out_size, void* d_ws, size_t ws_size,
                              hipStream_t stream) {
  const void* in[37];
  for (int i = 0; i < 37 && i < n_in; ++i) in[i] = d_in[i];
  char* ws = (char*)d_ws;

  detect_dtype<<<1, 64, 0, stream>>>(in[0], ws);

  S1Args a1;
  a1.z = in[2];
  const int wi[10] = {9, 14, 19, 24, 11, 16, 21, 26, 31, 33};
  const int bi[10] = {10, 15, 20, 25, 12, 17, 22, 27, 32, 34};
  for (int i = 0; i < 10; ++i) { a1.w[i] = in[wi[i]]; a1.b[i] = in[bi[i]]; }
  setup_vec<<<10, 256, 0, stream>>>(a1, ws);

  S2Args a2{in[6], in[7], in[4], in[8], in[13], in[18], in[30], in[23], in[5]};
  setup_w<<<1537, 256, 0, stream>>>(a2, ws);

  mlp_main<<<512, 512, 0, stream>>>(in[0], in[1], in[3], in[28], in[29], in[35], in[36],
                                    (const char*)ws, d_out);
}